// Round 3
// baseline (5945.151 us; speedup 1.0000x reference)
//
#include <hip/hip_runtime.h>

// LSTM w/ hard-sigmoid gates. T=512, B=64, I=H=512.
// Persistent kernel: 4 replicas (16 batches) x 16 WGs (512 thr = 8 waves).
//
// Round 3: gate-interleaved weight rows -- wave's 16 A-rows = {i,f,g,o} x 4 js,
// so C/D frag gives each lane (i,f,g,o) of ONE (batch,j): update is lane-local,
// NO LDS exchange. Flag-line barrier (16 plain stores, no RMW convoy), wave0
// polls, one __syncthreads per phase. All cross-WG data via sc0+sc1 (L1/L2
// bypass, device-coherent at L3); ordering = vmcnt(0) drain before flag store.
//
// Workspace: [0,4096)    : per-replica flag lines (rep*256B, 16 u32 each)
//            [4096,+128K): h double buffer [2][64][512] bf16

#define T_LEN 512
#define BATCH 64
#define ISZ   512
#define HSZ   512

#define NREP       4
#define WG_PER_REP 16
#define BR         16   // batches per replica
#define JW         32   // h columns per WG
#define NWG   (NREP * WG_PER_REP)
#define NTHR  512

typedef __bf16 bf16x8 __attribute__((ext_vector_type(8)));
typedef float  f32x4  __attribute__((ext_vector_type(4)));
typedef float  f32x8  __attribute__((ext_vector_type(8)));
typedef int    i32x4  __attribute__((ext_vector_type(4)));

__device__ __forceinline__ bf16x8 cvt8(const float4 a, const float4 b) {
  f32x8 t;
  t[0] = a.x; t[1] = a.y; t[2] = a.z; t[3] = a.w;
  t[4] = b.x; t[5] = b.y; t[6] = b.z; t[7] = b.w;
  return __builtin_convertvector(t, bf16x8);
}

__device__ __forceinline__ float fast_tanh(float v) {
  float e = __expf(2.0f * v);
  return 1.0f - 2.0f / (e + 1.0f);   // exact limits at +-inf
}

__device__ __forceinline__ float hsig(float v) {
  return fminf(fmaxf(0.2f * v + 0.5f, 0.0f), 1.0f);
}

// sc0 sc1 = bypass L1+L2, served at the device-coherent point (L3)
#define HLOAD(i, o)                                                        \
  asm volatile("global_load_dwordx4 %0, %1, off offset:" #o " sc0 sc1"     \
               : "=v"(hfrag[i]) : "v"(hr));

__global__ __launch_bounds__(NTHR, 2) void lstm_kernel(
    const float* __restrict__ x,      // [T][B][I]
    const float* __restrict__ h0,     // [B][H]
    const float* __restrict__ c0,     // [B][H]
    const float* __restrict__ w_ih,   // [4H][I]
    const float* __restrict__ w_hh,   // [4H][H]
    const float* __restrict__ b_ih,   // [4H]
    const float* __restrict__ b_hh,   // [4H]
    float* __restrict__ out,          // [T][B][H] ++ hn[B][H] ++ cn[B][H]
    unsigned* __restrict__ flags,     // per-replica 16-word flag line, 256B apart
    __bf16* __restrict__ hbuf)        // [2][B][H]
{
  const int bid = blockIdx.x;
  // bid%8 round-robins XCDs: replica r's 16 WGs sit on XCDs {2r, 2r+1}
  const int rep = (bid >> 1) & 3;
  const int wgi = ((bid >> 3) << 1) | (bid & 1);
  const int B0  = rep * BR;
  const int J0  = wgi * JW;

  const int tid  = threadIdx.x;
  const int lane = tid & 63;
  const int wv   = tid >> 6;          // 0..7
  const int l15  = lane & 15;         // MFMA col -> batch
  const int hi   = lane >> 4;         // 0..3
  const int lk   = hi << 3;           // k offset of this lane's 8-elem frag

  unsigned* myf = flags + rep * 64;   // 16 words used; replica lines 256B apart

  // lane-local output coordinates (from C/D frag: col=lane&15, row=hi*4+r)
  // A-row m (0..15): gate = m&3, j = J0 + 4*wv + (m>>2)  =>  acc[r] = gate r
  const int jl = J0 + 4 * wv + hi;            // this lane's j
  const size_t brow = (size_t)(B0 + l15);     // this lane's batch

  // ---- weights -> registers (gate-interleaved A-rows) ----
  bf16x8 wfrag[32];
  {
    const int grow = (l15 & 3) * HSZ + J0 + 4 * wv + (l15 >> 2);
    const float* wi = w_ih + (size_t)grow * ISZ + lk;
    const float* wh = w_hh + (size_t)grow * HSZ + lk;
#pragma unroll
    for (int kc = 0; kc < 16; ++kc) {
      float4 a = *(const float4*)(wi + kc * 32);
      float4 b = *(const float4*)(wi + kc * 32 + 4);
      wfrag[kc] = cvt8(a, b);
    }
#pragma unroll
    for (int kc = 0; kc < 16; ++kc) {
      float4 a = *(const float4*)(wh + kc * 32);
      float4 b = *(const float4*)(wh + kc * 32 + 4);
      wfrag[16 + kc] = cvt8(a, b);
    }
  }

  // ---- bias: acc[r] = gate r at column jl ----
  float bias[4];
#pragma unroll
  for (int r = 0; r < 4; ++r) bias[r] = b_ih[r * HSZ + jl] + b_hh[r * HSZ + jl];

  // ---- cell state + h0 publish (lane-local) ----
  float cst = c0[brow * HSZ + jl];
  __hip_atomic_store(&hbuf[brow * HSZ + jl], (__bf16)h0[brow * HSZ + jl],
                     __ATOMIC_RELAXED, __HIP_MEMORY_SCOPE_AGENT);

  __syncthreads();                    // per-wave vmcnt(0) drain before barrier
  if (tid == 0)
    __hip_atomic_store(&myf[wgi], 1u, __ATOMIC_RELAXED, __HIP_MEMORY_SCOPE_AGENT);

  for (int t = 0; t < T_LEN; ++t) {
    f32x4 acc;
    acc[0] = bias[0]; acc[1] = bias[1]; acc[2] = bias[2]; acc[3] = bias[3];

    // x contribution -- independent of the recurrence, overlaps the spin below
    const float* xr = x + ((size_t)t * BATCH + brow) * ISZ + lk;
#pragma unroll
    for (int kc = 0; kc < 16; ++kc) {
      float4 a = *(const float4*)(xr + kc * 32);
      float4 b = *(const float4*)(xr + kc * 32 + 4);
      acc = __builtin_amdgcn_mfma_f32_16x16x32_bf16(wfrag[kc], cvt8(a, b), acc, 0, 0, 0);
    }

    // wave 0 polls the 16-WG flag line (one coalesced 64B read per poll)
    if (wv == 0) {
      const unsigned tgt = (unsigned)(t + 1);
      long guard = 0;
      for (;;) {
        unsigned v = __hip_atomic_load(&myf[l15], __ATOMIC_RELAXED,
                                       __HIP_MEMORY_SCOPE_AGENT);
        if (__all((int)(v >= tgt))) break;
        __builtin_amdgcn_s_sleep(1);
        if (++guard > (1L << 22)) break;   // safety net: corrupt, don't hang
      }
    }
    __syncthreads();                   // releases waves 1..7
    __builtin_amdgcn_sched_barrier(0);

    // h contribution: B-frags from the global double buffer, L2-bypassing
    const __bf16* hr = hbuf + (size_t)(t & 1) * BATCH * HSZ + brow * HSZ + lk;
    i32x4 hfrag[16];
    HLOAD(0, 0)    HLOAD(1, 64)   HLOAD(2, 128)  HLOAD(3, 192)
    HLOAD(4, 256)  HLOAD(5, 320)  HLOAD(6, 384)  HLOAD(7, 448)
    HLOAD(8, 512)  HLOAD(9, 576)  HLOAD(10, 640) HLOAD(11, 704)
    HLOAD(12, 768) HLOAD(13, 832) HLOAD(14, 896) HLOAD(15, 960)
    asm volatile("s_waitcnt vmcnt(0)" ::: "memory");
    __builtin_amdgcn_sched_barrier(0);   // rule #18: keep MFMAs below the wait

#pragma unroll
    for (int kc = 0; kc < 16; ++kc) {
      bf16x8 hb = __builtin_bit_cast(bf16x8, hfrag[kc]);
      acc = __builtin_amdgcn_mfma_f32_16x16x32_bf16(wfrag[16 + kc], hb, acc, 0, 0, 0);
    }

    // lane-local cell update: acc = (i, f, g, o) for (brow, jl)
    float iv = hsig(acc[0]), fv = hsig(acc[1]), ov = hsig(acc[3]);
    float gv = fast_tanh(acc[2]);
    cst = fv * cst + iv * gv;
    float hv = ov * fast_tanh(cst);

    // publish h_{t+1} (2B sc store; 4 lanes/batch-row merge into 8B sectors)
    __hip_atomic_store(&hbuf[(size_t)((t + 1) & 1) * BATCH * HSZ + brow * HSZ + jl],
                       (__bf16)hv, __ATOMIC_RELAXED, __HIP_MEMORY_SCOPE_AGENT);

    __syncthreads();                   // every wave drains vmcnt(0) pre-barrier
    if (tid == 0)
      __hip_atomic_store(&myf[wgi], (unsigned)(t + 2), __ATOMIC_RELAXED,
                         __HIP_MEMORY_SCOPE_AGENT);

    // out stores off the critical path (plain cached stores, L2-merged)
    out[(size_t)t * BATCH * HSZ + brow * HSZ + jl] = hv;
    if (t == T_LEN - 1) {
      out[(size_t)T_LEN * BATCH * HSZ + brow * HSZ + jl] = hv;                        // hn
      out[(size_t)T_LEN * BATCH * HSZ + (size_t)BATCH * HSZ + brow * HSZ + jl] = cst; // cn
    }
  }
}

extern "C" void kernel_launch(void* const* d_in, const int* in_sizes, int n_in,
                              void* d_out, int out_size, void* d_ws, size_t ws_size,
                              hipStream_t stream) {
  const float* x    = (const float*)d_in[0];
  const float* h0   = (const float*)d_in[1];
  const float* c0   = (const float*)d_in[2];
  const float* w_ih = (const float*)d_in[3];
  const float* w_hh = (const float*)d_in[4];
  const float* b_ih = (const float*)d_in[5];
  const float* b_hh = (const float*)d_in[6];
  float* out = (float*)d_out;

  unsigned* flags = (unsigned*)d_ws;
  __bf16* hbuf    = (__bf16*)((char*)d_ws + 4096);
  // needs 4096 + 2*64*512*2 = ~132KB of workspace

  hipMemsetAsync(d_ws, 0, 4096, stream);  // zero flag lines (ws is poisoned)

  hipLaunchKernelGGL(lstm_kernel, dim3(NWG), dim3(NTHR), 0, stream,
                     x, h0, c0, w_ih, w_hh, b_ih, b_hh, out, flags, hbuf);
}

// Round 4
// 1578.956 us; speedup vs baseline: 3.7652x; 3.7652x over previous
//
#include <hip/hip_runtime.h>

// LSTM w/ hard-sigmoid gates. T=512, B=64, I=H=512.
// R4: SPLIT-K persistent kernel. 64 WGs (1/CU), 4 replicas x 16 WGs.
// WG owns 32 j-columns x 16 batches; its 8 waves split K=1024 into 128-slices:
//   waves 0-3: x-half (w_ih), never poll -- prefetch x[t+1] into registers
//   waves 4-7: h-half (w_hh), poll flags, sc0sc1 h loads from L3
// Partials reduced via 64KB LDS; gate rows interleaved (row=4j+gate) so the
// reduced f32x4 = (i,f,g,o) of one (batch,j): lane-local cell update.
// R3 lesson: per-wave operand redundancy (384KB/CU/step) was the bottleneck;
// split-K reads x and h exactly once per WG (48KB/CU/step).
//
// Workspace: [0,4096)    : per-replica flag lines (rep*256B, 16 u32)
//            [4096,+128K): h double buffer [2][64][512] bf16

#define T_LEN 512
#define BATCH 64
#define ISZ   512
#define HSZ   512

#define NREP 4
#define WPR  16
#define BR   16
#define JW   32
#define NWG  (NREP * WPR)
#define NTHR 512

typedef __bf16 bf16x8 __attribute__((ext_vector_type(8)));
typedef float  f32x4  __attribute__((ext_vector_type(4)));
typedef float  f32x8  __attribute__((ext_vector_type(8)));
typedef int    i32x4  __attribute__((ext_vector_type(4)));

__device__ __forceinline__ bf16x8 cvt8(f32x4 a, f32x4 b) {
  f32x8 t;
  t[0]=a[0]; t[1]=a[1]; t[2]=a[2]; t[3]=a[3];
  t[4]=b[0]; t[5]=b[1]; t[6]=b[2]; t[7]=b[3];
  return __builtin_convertvector(t, bf16x8);   // v_cvt_pk_bf16_f32 pairs
}

__device__ __forceinline__ float fast_tanh(float v) {
  float e = __expf(2.0f * v);
  return 1.0f - 2.0f / (e + 1.0f);   // exact limits at +-inf
}

__device__ __forceinline__ float hsig(float v) {
  return fminf(fmaxf(0.2f * v + 0.5f, 0.0f), 1.0f);
}

__device__ __forceinline__ unsigned pack_bf16(float a, float b) {
  union { __bf16 h[2]; unsigned u; } p;
  p.h[0] = (__bf16)a; p.h[1] = (__bf16)b;
  return p.u;
}

// h loads: sc0 sc1 = bypass L1/L2, served at the device-coherent L3
#define HLOAD(i, o)                                                        \
  asm volatile("global_load_dwordx4 %0, %1, off offset:" #o " sc0 sc1"     \
               : "=v"(hfrag[i]) : "v"(hr));
// x prefetch: plain cached loads, asm-pinned so they issue at the step tail
#define XLOAD(i, o)                                                        \
  asm volatile("global_load_dwordx4 %0, %1, off offset:" #o                \
               : "=v"(xpre[i]) : "v"(xr));

__global__ __launch_bounds__(NTHR, 2) void lstm_kernel(
    const float* __restrict__ x,      // [T][B][I]
    const float* __restrict__ h0,     // [B][H]
    const float* __restrict__ c0,     // [B][H]
    const float* __restrict__ w_ih,   // [4H][I]
    const float* __restrict__ w_hh,   // [4H][H]
    const float* __restrict__ b_ih,   // [4H]
    const float* __restrict__ b_hh,   // [4H]
    float* __restrict__ out,          // [T][B][H] ++ hn[B][H] ++ cn[B][H]
    unsigned* __restrict__ flags,     // per-replica 16-word flag line
    __bf16* __restrict__ hbuf)        // [2][B][H]
{
  const int bid = blockIdx.x;
  const int rep = bid >> 4;           // 0..3
  const int wgi = bid & 15;           // 0..15
  const int B0  = rep * BR;
  const int J0  = wgi * JW;

  const int tid  = threadIdx.x;
  const int lane = tid & 63;
  const int wv   = tid >> 6;          // 0..7
  const int l15  = lane & 15;
  const int hi   = lane >> 4;         // 0..3
  const bool xw  = (wv < 4);          // x-wave vs h-wave
  const int  K0  = (wv & 3) * 128;    // this wave's K-slice base

  unsigned* myf    = flags + rep * 64;
  unsigned* hbuf32 = (unsigned*)hbuf;

  // ---- weights -> registers: 128 interleaved rows (row=4*j_local+gate),
  //      K-slice [K0,K0+128) of w_ih (x-waves) or w_hh (h-waves) ----
  bf16x8 wfrag[32];                   // [tile 0..7][ks 0..3]
  {
    const float* W = xw ? w_ih : w_hh;
#pragma unroll
    for (int tile = 0; tile < 8; ++tile) {
      const int r    = tile * 16 + l15;              // WG-local row (A: row=l15)
      const int grow = (r & 3) * HSZ + J0 + (r >> 2);
      const float* wp = W + (size_t)grow * 512 + K0 + hi * 8;
#pragma unroll
      for (int ks = 0; ks < 4; ++ks) {
        f32x4 a = *(const f32x4*)(wp + ks * 32);
        f32x4 b = *(const f32x4*)(wp + ks * 32 + 4);
        wfrag[tile * 4 + ks] = cvt8(a, b);
      }
    }
  }

  // ---- update-phase ids: thread owns (batch ub, column uj) ----
  const int ub     = tid >> 5;        // 0..15
  const int uj     = tid & 31;        // 0..31
  const int tile_u = uj >> 2;
  const int hi_u   = uj & 3;
  const size_t urow = (size_t)(B0 + ub) * HSZ + (size_t)(J0 + uj);

  f32x4 bias4;
#pragma unroll
  for (int q = 0; q < 4; ++q)
    bias4[q] = b_ih[q * HSZ + J0 + uj] + b_hh[q * HSZ + J0 + uj];

  float cst = c0[urow];
  {
    float hv0 = h0[urow];
    float hp  = __shfl_xor(hv0, 1);
    if (!(tid & 1))
      __hip_atomic_store(&hbuf32[urow >> 1], pack_bf16(hv0, hp),
                         __ATOMIC_RELAXED, __HIP_MEMORY_SCOPE_AGENT);
  }

  // ---- x[0] register prefetch (x-waves) ----
  f32x4 xpre[8];
  if (xw) {
    const float* xr = x + ((size_t)0 * BATCH + B0 + l15) * ISZ + K0 + hi * 8;
    XLOAD(0, 0)   XLOAD(1, 16)  XLOAD(2, 128) XLOAD(3, 144)
    XLOAD(4, 256) XLOAD(5, 272) XLOAD(6, 384) XLOAD(7, 400)
  }

  __syncthreads();                    // drains h0 publish + x[0] prefetch
  if (tid == 0)
    __hip_atomic_store(&myf[wgi], 1u, __ATOMIC_RELAXED, __HIP_MEMORY_SCOPE_AGENT);

  // partials: [wave][tile][batch][hi] f32x4 = 64KB
  __shared__ f32x4 lds_p[8][8][16][4];

  for (int t = 0; t < T_LEN; ++t) {
    f32x4 acc[8];
#pragma unroll
    for (int i = 0; i < 8; ++i) acc[i] = (f32x4)(0.0f);

    if (xw) {
      // x[t] was prefetched; prior barrier did NOT drain it (issued after),
      // so wait here, then keep cvt/MFMA below the wait (rule #18)
      asm volatile("s_waitcnt vmcnt(0)" ::: "memory");
      __builtin_amdgcn_sched_barrier(0);
      bf16x8 bx[4];
#pragma unroll
      for (int ks = 0; ks < 4; ++ks) bx[ks] = cvt8(xpre[2 * ks], xpre[2 * ks + 1]);
#pragma unroll
      for (int tile = 0; tile < 8; ++tile)
#pragma unroll
        for (int ks = 0; ks < 4; ++ks)
          acc[tile] = __builtin_amdgcn_mfma_f32_16x16x32_bf16(
              wfrag[tile * 4 + ks], bx[ks], acc[tile], 0, 0, 0);
    } else {
      // h-waves: wait until all 16 WGs of this replica published h_t
      const unsigned tgt = (unsigned)(t + 1);
      long guard = 0;
      for (;;) {
        unsigned v = __hip_atomic_load(&myf[l15], __ATOMIC_RELAXED,
                                       __HIP_MEMORY_SCOPE_AGENT);
        if (__all((int)(v >= tgt))) break;
        __builtin_amdgcn_s_sleep(1);
        if (++guard > (1L << 22)) break;   // safety: corrupt, don't hang
      }
      __builtin_amdgcn_sched_barrier(0);

      const __bf16* hr = hbuf + (size_t)(t & 1) * BATCH * HSZ
                              + (size_t)(B0 + l15) * HSZ + K0 + hi * 8;
      i32x4 hfrag[4];
      HLOAD(0, 0) HLOAD(1, 64) HLOAD(2, 128) HLOAD(3, 192)
      asm volatile("s_waitcnt vmcnt(0)" ::: "memory");
      __builtin_amdgcn_sched_barrier(0);
#pragma unroll
      for (int tile = 0; tile < 8; ++tile)
#pragma unroll
        for (int ks = 0; ks < 4; ++ks)
          acc[tile] = __builtin_amdgcn_mfma_f32_16x16x32_bf16(
              wfrag[tile * 4 + ks], __builtin_bit_cast(bf16x8, hfrag[ks]),
              acc[tile], 0, 0, 0);
    }

#pragma unroll
    for (int tile = 0; tile < 8; ++tile)
      lds_p[wv][tile][l15][hi] = acc[tile];

    __syncthreads();                   // #1: partials visible

    // reduce 8 K-slices + bias -> (i,f,g,o) of (ub, uj); lane-local update
    f32x4 g = bias4;
#pragma unroll
    for (int w = 0; w < 8; ++w) g += lds_p[w][tile_u][ub][hi_u];

    float iv = hsig(g[0]), fv = hsig(g[1]), ov = hsig(g[3]);
    float gv = fast_tanh(g[2]);
    cst = fv * cst + iv * gv;
    float hv = ov * fast_tanh(cst);

    float hp = __shfl_xor(hv, 1);
    if (!(tid & 1))
      __hip_atomic_store(
          &hbuf32[((size_t)((t + 1) & 1) * BATCH * HSZ + urow) >> 1],
          pack_bf16(hv, hp), __ATOMIC_RELAXED, __HIP_MEMORY_SCOPE_AGENT);

    __syncthreads();                   // #2: drains publishes (vmcnt 0)
    if (tid == 0)
      __hip_atomic_store(&myf[wgi], (unsigned)(t + 2), __ATOMIC_RELAXED,
                         __HIP_MEMORY_SCOPE_AGENT);

    // off-critical-path: out stores (drained at next step's barrier #1)
    out[(size_t)t * BATCH * HSZ + urow] = hv;
    if (t == T_LEN - 1) {
      out[(size_t)T_LEN * BATCH * HSZ + urow] = hv;                        // hn
      out[(size_t)T_LEN * BATCH * HSZ + (size_t)BATCH * HSZ + urow] = cst; // cn
    }

    // x[t+1] register prefetch -- a full step of latency cover
    if (xw && (t + 1) < T_LEN) {
      const float* xr = x + ((size_t)(t + 1) * BATCH + B0 + l15) * ISZ + K0 + hi * 8;
      XLOAD(0, 0)   XLOAD(1, 16)  XLOAD(2, 128) XLOAD(3, 144)
      XLOAD(4, 256) XLOAD(5, 272) XLOAD(6, 384) XLOAD(7, 400)
    }
  }
}

extern "C" void kernel_launch(void* const* d_in, const int* in_sizes, int n_in,
                              void* d_out, int out_size, void* d_ws, size_t ws_size,
                              hipStream_t stream) {
  const float* x    = (const float*)d_in[0];
  const float* h0   = (const float*)d_in[1];
  const float* c0   = (const float*)d_in[2];
  const float* w_ih = (const float*)d_in[3];
  const float* w_hh = (const float*)d_in[4];
  const float* b_ih = (const float*)d_in[5];
  const float* b_hh = (const float*)d_in[6];
  float* out = (float*)d_out;

  unsigned* flags = (unsigned*)d_ws;
  __bf16* hbuf    = (__bf16*)((char*)d_ws + 4096);
  // needs 4096 + 2*64*512*2 = ~132KB of workspace

  hipMemsetAsync(d_ws, 0, 4096, stream);  // zero flag lines (ws is poisoned)

  hipLaunchKernelGGL(lstm_kernel, dim3(NWG), dim3(NTHR), 0, stream,
                     x, h0, c0, w_ih, w_hh, b_ih, b_hh, out, flags, hbuf);
}